// Round 3
// baseline (341.457 us; speedup 1.0000x reference)
//
#include <hip/hip_runtime.h>
#include <cstdint>

// ---------------------------------------------------------------------------
// PaddedSoftmaxSHCSA: y = softmax(mask(scale * (xW+b)_q @ (xW+b)_k^T)) @ (xW+b)_v
// T=4096, C=2048, NF=2048, 3*NF=6144. fp32 in/out, bf16 MFMA compute.
//
// Round 10: attack the serial (MFMA + LDS-read) per-K-tile model.
//  * qkv: 256x384 block, 8 waves, per-wave 128x96 (acc 8x6xf32x4=192 VGPR).
//    LDS traffic/FLOP -42% vs 64x64 waves. Ring-2 160 KiB LDS, counted
//    vmcnt(10) lead-1 prefetch, dual raw s_barrier, setprio on MFMA cluster.
//    Grid 16x16 = 256 blocks = ONE perfect round on 256 CUs.
//  * gemm_loop (sc/pv): ring-2 + counted vmcnt(8) + dual barrier — removes
//    the stage->syncthreads HBM-latency drain (~400-900 cy) per K-tile.
// Keep: 8-chunk XOR swizzle (0 conflicts), triangular sc grid, wave-per-row
// softmax, pv split-K stragglers, prep fusion.
// ---------------------------------------------------------------------------

#define T_DIM 4096
#define C_DIM 2048
#define NF    2048
#define N3    6144
#define NEGV  (-1e30f)

typedef __bf16 bf16x8 __attribute__((ext_vector_type(8)));
typedef __bf16 bf16x4 __attribute__((ext_vector_type(4)));
typedef float  f32x4  __attribute__((ext_vector_type(4)));

__device__ __forceinline__ void async_cp16(const void* g, void* l) {
    __builtin_amdgcn_global_load_lds(
        reinterpret_cast<const __attribute__((address_space(1))) unsigned int*>(
            reinterpret_cast<uintptr_t>(g)),
        reinterpret_cast<__attribute__((address_space(3))) unsigned int*>(
            reinterpret_cast<uintptr_t>(l)),
        16, 0, 0);
}

// Shared 128x128-tile GEMM K-loop, BK=64, ring-2 counted-vmcnt:
// C[m0..+128, n0..+128] += A @ B^T.  A: (M x K) row-major, lda; B: (N x K),
// ldb. As/Bs: [2][128*64] rings. 8-chunk XOR swizzle, 0 bank conflicts.
// Per K-tile: stage(kt+1) -> vmcnt(8) [stage(kt) landed] -> BAR -> compute
// -> BAR [protect slot before next-iter overwrite]. No vmcnt(0) drain in
// the main loop; lead-1 prefetch hides HBM latency under compute.
__device__ __forceinline__ void gemm_loop(const __bf16* A, const __bf16* B,
                                          int lda, int ldb, int m0, int n0,
                                          int kiters, __bf16* As, __bf16* Bs,
                                          f32x4 (&acc)[4][4]) {
    if (kiters <= 0) return;
    const int t    = threadIdx.x;          // 0..255
    const int wv   = t >> 6;               // wave 0..3
    const int lane = t & 63;
    const int srow = t >> 3;               // staging row 0..31 (issue 0)
    const int scol = (((t & 7) ^ (srow & 7)) << 3);  // pre-swizzled src chunk
    const int wm   = (wv >> 1) << 6;       // wave m offset 0/64
    const int wn   = (wv & 1) << 6;        // wave n offset 0/64
    const int lrow = lane & 15;
    const int kq   = lane >> 4;            // logical chunk within k-step 0..3
    const int swz  = lrow & 7;             // 16/32/64 row offsets preserve &7
    const int rc0  = ((kq ^ swz) << 3);         // k-step 0: chunks 0..3
    const int rc1  = (((kq | 4) ^ swz) << 3);   // k-step 1: chunks 4..7

    const __bf16* ga = A + (size_t)(m0 + srow) * lda + scol;
    const __bf16* gb = B + (size_t)(n0 + srow) * ldb + scol;

    auto stage = [&](int kk, int s) {
#pragma unroll
        for (int i = 0; i < 4; ++i) {
            async_cp16(ga + kk * 64 + (size_t)(32 * i) * lda,
                       &As[s * 8192 + i * 2048 + wv * 512]);
            async_cp16(gb + kk * 64 + (size_t)(32 * i) * ldb,
                       &Bs[s * 8192 + i * 2048 + wv * 512]);
        }
    };

    stage(0, 0);
    int buf = 0;
    for (int kk = 0; kk < kiters; ++kk) {
        if (kk + 1 < kiters) {
            stage(kk + 1, buf ^ 1);
            asm volatile("s_waitcnt vmcnt(8)" ::: "memory");
        } else {
            asm volatile("s_waitcnt vmcnt(0)" ::: "memory");
        }
        __builtin_amdgcn_s_barrier();      // all waves' stage(kk) landed
        asm volatile("" ::: "memory");
        const __bf16* Ab = &As[buf * 8192];
        const __bf16* Bb = &Bs[buf * 8192];
#pragma unroll
        for (int kb = 0; kb < 2; ++kb) {
            const int rc = kb ? rc1 : rc0;
            bf16x8 af[4], bfr[4];
#pragma unroll
            for (int mi = 0; mi < 4; ++mi)
                af[mi] = *(const bf16x8*)&Ab[(wm + mi * 16 + lrow) * 64 + rc];
#pragma unroll
            for (int ni = 0; ni < 4; ++ni)
                bfr[ni] = *(const bf16x8*)&Bb[(wn + ni * 16 + lrow) * 64 + rc];
            __builtin_amdgcn_s_setprio(1);
#pragma unroll
            for (int mi = 0; mi < 4; ++mi)
#pragma unroll
                for (int ni = 0; ni < 4; ++ni)
                    acc[mi][ni] = __builtin_amdgcn_mfma_f32_16x16x32_bf16(
                        af[mi], bfr[ni], acc[mi][ni], 0, 0, 0);
            __builtin_amdgcn_s_setprio(0);
        }
        asm volatile("" ::: "memory");
        __builtin_amdgcn_s_barrier();      // protect slot buf before overwrite
        buf ^= 1;
    }
}

// ---------------- 1. prep: cast x -> bf16  AND  transpose-cast W -----------
__global__ void prep_kernel(const float* __restrict__ x,
                            __bf16* __restrict__ xb,
                            const float* __restrict__ W,
                            __bf16* __restrict__ Wt) {
    if (blockIdx.x < 2048) {
        const int n4 = (T_DIM * C_DIM) / 4;
        const int stride = 2048 * 256;
        for (int i = blockIdx.x * 256 + threadIdx.x; i < n4; i += stride) {
            float4 v = ((const float4*)x)[i];
            bf16x4 o;
            o[0] = (__bf16)v.x; o[1] = (__bf16)v.y;
            o[2] = (__bf16)v.z; o[3] = (__bf16)v.w;
            ((bf16x4*)xb)[i] = o;
        }
        return;
    }
    __shared__ float tile[32][33];
    const int tb = blockIdx.x - 2048;
    const int bx = (tb % (N3 / 32)) * 32;  // W col / Wt row
    const int by = (tb / (N3 / 32)) * 32;  // W row / Wt col
    const int tx = threadIdx.x & 31, ty = threadIdx.x >> 5;  // (32,8)
#pragma unroll
    for (int i = 0; i < 32; i += 8)
        tile[ty + i][tx] = W[(size_t)(by + ty + i) * N3 + bx + tx];
    __syncthreads();
#pragma unroll
    for (int i = 0; i < 32; i += 8)
        Wt[(size_t)(bx + ty + i) * C_DIM + by + tx] = (__bf16)tile[tx][ty + i];
}

// epilogue helpers for 16x16 C/D: col=lane&15, row=(lane>>4)*4+r
#define EPILOG_SETUP()                                     \
    const int t = threadIdx.x, wv = t >> 6, lane = t & 63; \
    const int wm = (wv >> 1) << 6, wn = (wv & 1) << 6;     \
    const int rq = (lane >> 4) << 2, cn = lane & 15

// ---------------- 3. QKV GEMM: 256x384 block, 8 waves of 128x96 ------------
// Ring-2 LDS (A 2x32KB + B 2x48KB = 160 KiB), counted vmcnt(10) lead-1,
// dual raw barrier. Grid 16x16 = 256 blocks = one perfect round.
__global__ void __launch_bounds__(512)
qkv_gemm_kernel(const __bf16* __restrict__ xb, const __bf16* __restrict__ Wt,
                const float* __restrict__ bias, __bf16* __restrict__ qb,
                __bf16* __restrict__ kb, __bf16* __restrict__ vT) {
    __shared__ __bf16 As[2][256 * 64];   // 64 KB
    __shared__ __bf16 Bs[2][384 * 64];   // 96 KB

    const int t    = threadIdx.x;        // 0..511
    const int wv   = t >> 6;             // wave 0..7
    const int lane = t & 63;
    const int srow = t >> 3;             // staging row 0..63 per issue
    const int scol = (((t & 7) ^ (srow & 7)) << 3);  // pre-swizzled src chunk
    const int m0   = blockIdx.x * 256;   // 16 m-tiles
    const int n0   = blockIdx.y * 384;   // 16 n-tiles
    const int wmo  = (wv >> 2) * 128;    // wave m offset 0/128
    const int wno  = (wv & 3) * 96;      // wave n offset 0/96/192/288
    const int lrow = lane & 15;
    const int kq   = lane >> 4;
    const int swz  = lrow & 7;
    const int rc0  = ((kq ^ swz) << 3);
    const int rc1  = (((kq | 4) ^ swz) << 3);

    const __bf16* ga = xb + (size_t)(m0 + srow) * C_DIM + scol;
    const __bf16* gb = Wt + (size_t)(n0 + srow) * C_DIM + scol;

    f32x4 acc[8][6] = {};

    // stage K-tile kt into ring slot s: A 4 issues, B 6 issues (64 rows each)
    auto stage = [&](int kt, int s) {
        const __bf16* a  = ga + kt * 64;
        const __bf16* b2 = gb + kt * 64;
#pragma unroll
        for (int i = 0; i < 4; ++i)
            async_cp16(a + (size_t)(64 * i) * C_DIM, &As[s][i * 4096 + wv * 512]);
#pragma unroll
        for (int i = 0; i < 6; ++i)
            async_cp16(b2 + (size_t)(64 * i) * C_DIM, &Bs[s][i * 4096 + wv * 512]);
    };

    constexpr int KT = C_DIM / 64;  // 32
    stage(0, 0);
    int buf = 0;
    for (int kt = 0; kt < KT; ++kt) {
        if (kt + 1 < KT) {
            stage(kt + 1, buf ^ 1);
            // my stage(kt) landed once <=10 newer (stage(kt+1)) still fly
            asm volatile("s_waitcnt vmcnt(10)" ::: "memory");
        } else {
            asm volatile("s_waitcnt vmcnt(0)" ::: "memory");
        }
        __builtin_amdgcn_s_barrier();      // all waves' stage(kt) landed
        asm volatile("" ::: "memory");
        const __bf16* Ab = As[buf];
        const __bf16* Bb = Bs[buf];
#pragma unroll
        for (int kb2 = 0; kb2 < 2; ++kb2) {
            const int rc = kb2 ? rc1 : rc0;
            bf16x8 bfr[6];
#pragma unroll
            for (int ni = 0; ni < 6; ++ni)
                bfr[ni] = *(const bf16x8*)&Bb[(wno + ni * 16 + lrow) * 64 + rc];
            __builtin_amdgcn_s_setprio(1);
#pragma unroll
            for (int mi = 0; mi < 8; ++mi) {
                // stream af to keep VGPR pressure under 256
                bf16x8 af = *(const bf16x8*)&Ab[(wmo + mi * 16 + lrow) * 64 + rc];
#pragma unroll
                for (int ni = 0; ni < 6; ++ni)
                    acc[mi][ni] = __builtin_amdgcn_mfma_f32_16x16x32_bf16(
                        af, bfr[ni], acc[mi][ni], 0, 0, 0);
            }
            __builtin_amdgcn_s_setprio(0);
        }
        asm volatile("" ::: "memory");
        __builtin_amdgcn_s_barrier();      // protect slot buf before overwrite
        buf ^= 1;
    }

    // epilogue: q/k/v boundaries (2048, 4096) are 16-aligned -> per-frag
    // uniform region routing.
    const int rq = (lane >> 4) << 2, cn = lane & 15;
#pragma unroll
    for (int mi = 0; mi < 8; ++mi)
#pragma unroll
        for (int ni = 0; ni < 6; ++ni) {
            int col = n0 + wno + ni * 16 + cn;
            float bv = bias[col];
            if (col >= 2 * NF) {
                // vT rows r=0..3 contiguous: one bf16x4 store
                bf16x4 o;
#pragma unroll
                for (int r = 0; r < 4; ++r) o[r] = (__bf16)(acc[mi][ni][r] + bv);
                int row = m0 + wmo + mi * 16 + rq;
                *(bf16x4*)&vT[(size_t)(col - 2 * NF) * T_DIM + row] = o;
            } else {
#pragma unroll
                for (int r = 0; r < 4; ++r) {
                    int row = m0 + wmo + mi * 16 + rq + r;
                    float val = acc[mi][ni][r] + bv;
                    if (col < NF)
                        qb[(size_t)row * NF + col] = (__bf16)val;
                    else
                        kb[(size_t)row * NF + (col - NF)] = (__bf16)val;
                }
            }
        }
}

// ---------------- 4. S = scale * q @ k^T (bf16; mask applied in softmax) ---
__global__ void __launch_bounds__(256)
sc_gemm_kernel(const __bf16* __restrict__ qb, const __bf16* __restrict__ kb,
               __bf16* __restrict__ S, const int* __restrict__ npadd_p) {
    int i = blockIdx.x;
    int mt = (int)((sqrtf(8.0f * (float)i + 1.0f) - 1.0f) * 0.5f);
    while ((mt + 1) * (mt + 2) / 2 <= i) ++mt;
    while (mt * (mt + 1) / 2 > i) --mt;
    int nt = i - mt * (mt + 1) / 2;
    const int m0 = mt * 128, n0 = nt * 128;
    const int npadd = *npadd_p;
    if (m0 + 128 <= npadd || n0 + 128 <= npadd) return;  // fully masked

    __shared__ __bf16 As[2 * 128 * 64];
    __shared__ __bf16 Bs[2 * 128 * 64];
    f32x4 acc[4][4] = {};
    gemm_loop(qb, kb, NF, NF, m0, n0, NF / 64, As, Bs, acc);

    const float scale = 0.022097086912079608f;  // 1/sqrt(2048)
    EPILOG_SETUP();
#pragma unroll
    for (int mi = 0; mi < 4; ++mi)
#pragma unroll
        for (int ni = 0; ni < 4; ++ni) {
            int j = n0 + wn + ni * 16 + cn;
#pragma unroll
            for (int r = 0; r < 4; ++r) {
                int row = m0 + wm + mi * 16 + rq + r;
                S[(size_t)row * T_DIM + j] = (__bf16)(acc[mi][ni][r] * scale);
            }
        }
}

// ---------------- 5. row softmax: one WAVE per row, no barriers ------------
__global__ void __launch_bounds__(256)
softmax_kernel(const __bf16* __restrict__ S, __bf16* __restrict__ P,
               const int* __restrict__ npadd_p) {
    const int wv = threadIdx.x >> 6, lane = threadIdx.x & 63;
    const int row = blockIdx.x * 4 + wv;
    const int npadd = *npadd_p;
    __bf16* prow = P + (size_t)row * T_DIM;

    if (row < npadd) {  // padding row: p == 0
        bf16x8 z = {};
#pragma unroll
        for (int c = 0; c < 8; ++c) ((bf16x8*)prow)[c * 64 + lane] = z;
        return;
    }

    const __bf16* srow = S + (size_t)row * T_DIM;
    float vals[64];
    float mx = NEGV;
#pragma unroll
    for (int c = 0; c < 8; ++c) {
        if (c * 512 > row) {  // wave-uniform skip
#pragma unroll
            for (int e = 0; e < 8; ++e) vals[c * 8 + e] = NEGV;
            continue;
        }
        int j0 = c * 512 + lane * 8;
        bf16x8 v = ((const bf16x8*)srow)[c * 64 + lane];
#pragma unroll
        for (int e = 0; e < 8; ++e) {
            float f = (j0 + e >= npadd && j0 + e <= row) ? (float)v[e] : NEGV;
            vals[c * 8 + e] = f;
            mx = fmaxf(mx, f);
        }
    }
#pragma unroll
    for (int o = 32; o > 0; o >>= 1) mx = fmaxf(mx, __shfl_xor(mx, o));

    float sm = 0.f;
#pragma unroll
    for (int k = 0; k < 64; ++k) {
        vals[k] = exp2f((vals[k] - mx) * 1.4426950408889634f);
        sm += vals[k];
    }
#pragma unroll
    for (int o = 32; o > 0; o >>= 1) sm += __shfl_xor(sm, o);
    float inv = 1.0f / sm;

#pragma unroll
    for (int c = 0; c < 8; ++c) {
        bf16x8 o;
#pragma unroll
        for (int e = 0; e < 8; ++e) o[e] = (__bf16)(vals[c * 8 + e] * inv);
        ((bf16x8*)prow)[c * 64 + lane] = o;
    }
}

// ---------------- 6. y = P @ V, split-K for the deep tiles -----------------
__global__ void __launch_bounds__(256)
pv_gemm_kernel(const __bf16* __restrict__ P, const __bf16* __restrict__ vT,
               float* __restrict__ out, const int* __restrict__ npadd_p) {
    const int idx = blockIdx.x;
    const int kskip = *npadd_p >> 6;  // BK=64 tiles fully inside padding
    int mt, nt, start, iters;
    bool atomic_out;
    if (idx < 256) {
        mt = idx & 15; nt = idx >> 4;
        int kt = (mt + 1) * 2 - kskip; if (kt < 0) kt = 0;
        start = kskip; iters = kt; atomic_out = false;
    } else {
        int j = idx - 256;
        mt = 16 + (j & 15); nt = (j >> 4) & 15;
        int half = j >> 8;
        int kt = (mt + 1) * 2 - kskip; if (kt < 0) kt = 0;
        int h0 = (kt + 1) >> 1;
        start = kskip + (half ? h0 : 0);
        iters = half ? kt - h0 : h0;
        atomic_out = true;
    }
    const int m0 = mt * 128, n0 = nt * 128;

    __shared__ __bf16 As[2 * 128 * 64];
    __shared__ __bf16 Bs[2 * 128 * 64];
    f32x4 acc[4][4] = {};
    gemm_loop(P + (size_t)start * 64, vT + (size_t)start * 64,
              T_DIM, T_DIM, m0, n0, iters, As, Bs, acc);

    EPILOG_SETUP();
#pragma unroll
    for (int mi = 0; mi < 4; ++mi)
#pragma unroll
        for (int ni = 0; ni < 4; ++ni) {
            int col = n0 + wn + ni * 16 + cn;
#pragma unroll
            for (int r = 0; r < 4; ++r) {
                int row = m0 + wm + mi * 16 + rq + r;
                float* p = &out[(size_t)row * NF + col];
                if (atomic_out) unsafeAtomicAdd(p, acc[mi][ni][r]);
                else            *p = acc[mi][ni][r];
            }
        }
}

extern "C" void kernel_launch(void* const* d_in, const int* in_sizes, int n_in,
                              void* d_out, int out_size, void* d_ws,
                              size_t ws_size, hipStream_t stream) {
    const float* x = (const float*)d_in[0];
    const float* W = (const float*)d_in[1];
    const float* b = (const float*)d_in[2];
    const int* npadd = (const int*)d_in[3];
    float* out = (float*)d_out;

    char* ws = (char*)d_ws;
    // layout (120 MB used):
    __bf16* xb = (__bf16*)(ws);                          // 16 MB [0,16)
    __bf16* Wt = (__bf16*)(ws + (16ull << 20));          // 24 MB [16,40)
    __bf16* qb = (__bf16*)(ws + (40ull << 20));          // 16 MB [40,56)
    __bf16* kb = (__bf16*)(ws + (56ull << 20));          // 16 MB [56,72)
    __bf16* vT = (__bf16*)(ws + (72ull << 20));          // 16 MB [72,88)
    __bf16* S  = (__bf16*)(ws + (88ull << 20));          // 32 MB [88,120)
    __bf16* P  = (__bf16*)(ws + (40ull << 20));          // 32 MB reuse qb+kb

    // zero the atomic-accumulated half of out (rows 2048..4095)
    hipMemsetAsync(out + (size_t)2048 * NF, 0, (size_t)2048 * NF * 4, stream);

    prep_kernel<<<2048 + (N3 / 32) * (C_DIM / 32), 256, 0, stream>>>(x, xb, W, Wt);
    qkv_gemm_kernel<<<dim3(T_DIM / 256, N3 / 384), 512, 0, stream>>>(xb, Wt, b,
                                                                     qb, kb, vT);
    sc_gemm_kernel<<<528, 256, 0, stream>>>(qb, kb, S, npadd);
    softmax_kernel<<<T_DIM / 4, 256, 0, stream>>>(S, P, npadd);
    pv_gemm_kernel<<<768, 256, 0, stream>>>(P, vT, out, npadd);
}

// Round 4
// 329.984 us; speedup vs baseline: 1.0348x; 1.0348x over previous
//
#include <hip/hip_runtime.h>
#include <cstdint>

// ---------------------------------------------------------------------------
// PaddedSoftmaxSHCSA: y = softmax(mask(scale * (xW+b)_q @ (xW+b)_k^T)) @ (xW+b)_v
// T=4096, C=2048, NF=2048, 3*NF=6144. fp32 in/out, bf16 MFMA compute.
//
// Round 11: qkv K-tile split into 4 fine phases (T3 structure). R3 evidence:
// coarse 2-barrier K-step runs reads/fills/MFMA serially (8175 cy/K-tile vs
// 3600 overlapped bound, MfmaUtil stuck at 40%). Per phase:
// {ds_read subtile -> BAR -> 24 MFMA (setprio) -> BAR}; stage issues spread
// P0/P1/P2 (A4,B3,B3); one vmcnt(0) at P3-end (youngest issue ~1 phase old
// -> counted-by-time, no real drain). 8 barriers/K-tile = m201 density.
// Keep: 256x384 block, 8 waves 128x96, ring-2 160 KiB LDS, 8-chunk XOR
// swizzle (0 conflicts), grid 16x16 = one perfect round.
// sc/softmax/pv/prep unchanged from R3.
// ---------------------------------------------------------------------------

#define T_DIM 4096
#define C_DIM 2048
#define NF    2048
#define N3    6144
#define NEGV  (-1e30f)

typedef __bf16 bf16x8 __attribute__((ext_vector_type(8)));
typedef __bf16 bf16x4 __attribute__((ext_vector_type(4)));
typedef float  f32x4  __attribute__((ext_vector_type(4)));

#define FENCE() asm volatile("" ::: "memory")
#define BARRIER() do { FENCE(); __builtin_amdgcn_s_barrier(); FENCE(); } while (0)

__device__ __forceinline__ void async_cp16(const void* g, void* l) {
    __builtin_amdgcn_global_load_lds(
        reinterpret_cast<const __attribute__((address_space(1))) unsigned int*>(
            reinterpret_cast<uintptr_t>(g)),
        reinterpret_cast<__attribute__((address_space(3))) unsigned int*>(
            reinterpret_cast<uintptr_t>(l)),
        16, 0, 0);
}

// Shared 128x128-tile GEMM K-loop, BK=64, ring-2 counted-vmcnt (sc/pv).
__device__ __forceinline__ void gemm_loop(const __bf16* A, const __bf16* B,
                                          int lda, int ldb, int m0, int n0,
                                          int kiters, __bf16* As, __bf16* Bs,
                                          f32x4 (&acc)[4][4]) {
    if (kiters <= 0) return;
    const int t    = threadIdx.x;          // 0..255
    const int wv   = t >> 6;               // wave 0..3
    const int lane = t & 63;
    const int srow = t >> 3;               // staging row 0..31 (issue 0)
    const int scol = (((t & 7) ^ (srow & 7)) << 3);  // pre-swizzled src chunk
    const int wm   = (wv >> 1) << 6;       // wave m offset 0/64
    const int wn   = (wv & 1) << 6;        // wave n offset 0/64
    const int lrow = lane & 15;
    const int kq   = lane >> 4;            // logical chunk within k-step 0..3
    const int swz  = lrow & 7;             // 16/32/64 row offsets preserve &7
    const int rc0  = ((kq ^ swz) << 3);         // k-step 0: chunks 0..3
    const int rc1  = (((kq | 4) ^ swz) << 3);   // k-step 1: chunks 4..7

    const __bf16* ga = A + (size_t)(m0 + srow) * lda + scol;
    const __bf16* gb = B + (size_t)(n0 + srow) * ldb + scol;

    auto stage = [&](int kk, int s) {
#pragma unroll
        for (int i = 0; i < 4; ++i) {
            async_cp16(ga + kk * 64 + (size_t)(32 * i) * lda,
                       &As[s * 8192 + i * 2048 + wv * 512]);
            async_cp16(gb + kk * 64 + (size_t)(32 * i) * ldb,
                       &Bs[s * 8192 + i * 2048 + wv * 512]);
        }
    };

    stage(0, 0);
    int buf = 0;
    for (int kk = 0; kk < kiters; ++kk) {
        if (kk + 1 < kiters) {
            stage(kk + 1, buf ^ 1);
            asm volatile("s_waitcnt vmcnt(8)" ::: "memory");
        } else {
            asm volatile("s_waitcnt vmcnt(0)" ::: "memory");
        }
        __builtin_amdgcn_s_barrier();      // all waves' stage(kk) landed
        FENCE();
        const __bf16* Ab = &As[buf * 8192];
        const __bf16* Bb = &Bs[buf * 8192];
#pragma unroll
        for (int kb = 0; kb < 2; ++kb) {
            const int rc = kb ? rc1 : rc0;
            bf16x8 af[4], bfr[4];
#pragma unroll
            for (int mi = 0; mi < 4; ++mi)
                af[mi] = *(const bf16x8*)&Ab[(wm + mi * 16 + lrow) * 64 + rc];
#pragma unroll
            for (int ni = 0; ni < 4; ++ni)
                bfr[ni] = *(const bf16x8*)&Bb[(wn + ni * 16 + lrow) * 64 + rc];
            __builtin_amdgcn_s_setprio(1);
#pragma unroll
            for (int mi = 0; mi < 4; ++mi)
#pragma unroll
                for (int ni = 0; ni < 4; ++ni)
                    acc[mi][ni] = __builtin_amdgcn_mfma_f32_16x16x32_bf16(
                        af[mi], bfr[ni], acc[mi][ni], 0, 0, 0);
            __builtin_amdgcn_s_setprio(0);
        }
        FENCE();
        __builtin_amdgcn_s_barrier();      // protect slot buf before overwrite
        buf ^= 1;
    }
}

// ---------------- 1. prep: cast x -> bf16  AND  transpose-cast W -----------
__global__ void prep_kernel(const float* __restrict__ x,
                            __bf16* __restrict__ xb,
                            const float* __restrict__ W,
                            __bf16* __restrict__ Wt) {
    if (blockIdx.x < 2048) {
        const int n4 = (T_DIM * C_DIM) / 4;
        const int stride = 2048 * 256;
        for (int i = blockIdx.x * 256 + threadIdx.x; i < n4; i += stride) {
            float4 v = ((const float4*)x)[i];
            bf16x4 o;
            o[0] = (__bf16)v.x; o[1] = (__bf16)v.y;
            o[2] = (__bf16)v.z; o[3] = (__bf16)v.w;
            ((bf16x4*)xb)[i] = o;
        }
        return;
    }
    __shared__ float tile[32][33];
    const int tb = blockIdx.x - 2048;
    const int bx = (tb % (N3 / 32)) * 32;  // W col / Wt row
    const int by = (tb / (N3 / 32)) * 32;  // W row / Wt col
    const int tx = threadIdx.x & 31, ty = threadIdx.x >> 5;  // (32,8)
#pragma unroll
    for (int i = 0; i < 32; i += 8)
        tile[ty + i][tx] = W[(size_t)(by + ty + i) * N3 + bx + tx];
    __syncthreads();
#pragma unroll
    for (int i = 0; i < 32; i += 8)
        Wt[(size_t)(bx + ty + i) * C_DIM + by + tx] = (__bf16)tile[tx][ty + i];
}

// epilogue helpers for 16x16 C/D: col=lane&15, row=(lane>>4)*4+r
#define EPILOG_SETUP()                                     \
    const int t = threadIdx.x, wv = t >> 6, lane = t & 63; \
    const int wm = (wv >> 1) << 6, wn = (wv & 1) << 6;     \
    const int rq = (lane >> 4) << 2, cn = lane & 15

// ---------------- 3. QKV GEMM: 256x384 block, 4 fine phases per K-tile -----
__global__ void __launch_bounds__(512)
qkv_gemm_kernel(const __bf16* __restrict__ xb, const __bf16* __restrict__ Wt,
                const float* __restrict__ bias, __bf16* __restrict__ qb,
                __bf16* __restrict__ kb, __bf16* __restrict__ vT) {
    __shared__ __bf16 As[2][256 * 64];   // 64 KB
    __shared__ __bf16 Bs[2][384 * 64];   // 96 KB

    const int t    = threadIdx.x;        // 0..511
    const int wv   = t >> 6;             // wave 0..7
    const int lane = t & 63;
    const int srow = t >> 3;             // staging row 0..63 per issue
    const int scol = (((t & 7) ^ (srow & 7)) << 3);  // pre-swizzled src chunk
    const int m0   = blockIdx.x * 256;   // 16 m-tiles
    const int n0   = blockIdx.y * 384;   // 16 n-tiles
    const int wmo  = (wv >> 2) * 128;    // wave m offset 0/128
    const int wno  = (wv & 3) * 96;      // wave n offset 0/96/192/288
    const int lrow = lane & 15;
    const int kq   = lane >> 4;
    const int swz  = lrow & 7;
    const int rc0  = ((kq ^ swz) << 3);
    const int rc1  = (((kq | 4) ^ swz) << 3);

    const __bf16* ga = xb + (size_t)(m0 + srow) * C_DIM + scol;
    const __bf16* gb = Wt + (size_t)(n0 + srow) * C_DIM + scol;

    f32x4 acc[8][6] = {};

    auto stageA = [&](int kt, int s) {   // 4 issues: A rows 0..255
        const __bf16* a = ga + kt * 64;
#pragma unroll
        for (int i = 0; i < 4; ++i)
            async_cp16(a + (size_t)(64 * i) * C_DIM, &As[s][i * 4096 + wv * 512]);
    };
    auto stageB = [&](int kt, int s, int h) {  // 3 issues: B rows h*192..+191
        const __bf16* b2 = gb + kt * 64;
#pragma unroll
        for (int i = 0; i < 3; ++i)
            async_cp16(b2 + (size_t)(64 * (h * 3 + i)) * C_DIM,
                       &Bs[s][(h * 3 + i) * 4096 + wv * 512]);
    };

    constexpr int KT = C_DIM / 64;  // 32

    // prologue: stage K-tile 0, drain, sync
    stageA(0, 0); stageB(0, 0, 0); stageB(0, 0, 1);
    asm volatile("s_waitcnt vmcnt(0)" ::: "memory");
    BARRIER();

    int buf = 0;
    for (int kt = 0; kt < KT; ++kt) {
        const __bf16* Ab = As[buf];
        const __bf16* Bb = Bs[buf];
        const bool pf = (kt + 1 < KT);
        bf16x8 bfr[6];

        // ---- P0: (kh0, mh0) + bfr(kh0); stage A(kt+1) ----
        if (pf) stageA(kt + 1, buf ^ 1);
        {
            bf16x8 af[4];
#pragma unroll
            for (int ni = 0; ni < 6; ++ni)
                bfr[ni] = *(const bf16x8*)&Bb[(wno + ni * 16 + lrow) * 64 + rc0];
#pragma unroll
            for (int mi = 0; mi < 4; ++mi)
                af[mi] = *(const bf16x8*)&Ab[(wmo + mi * 16 + lrow) * 64 + rc0];
            BARRIER();
            __builtin_amdgcn_s_setprio(1);
#pragma unroll
            for (int mi = 0; mi < 4; ++mi)
#pragma unroll
                for (int ni = 0; ni < 6; ++ni)
                    acc[mi][ni] = __builtin_amdgcn_mfma_f32_16x16x32_bf16(
                        af[mi], bfr[ni], acc[mi][ni], 0, 0, 0);
            __builtin_amdgcn_s_setprio(0);
            BARRIER();
        }
        // ---- P1: (kh0, mh1); stage B0(kt+1) ----
        if (pf) stageB(kt + 1, buf ^ 1, 0);
        {
            bf16x8 af[4];
#pragma unroll
            for (int mi = 0; mi < 4; ++mi)
                af[mi] = *(const bf16x8*)&Ab[(wmo + 64 + mi * 16 + lrow) * 64 + rc0];
            BARRIER();
            __builtin_amdgcn_s_setprio(1);
#pragma unroll
            for (int mi = 0; mi < 4; ++mi)
#pragma unroll
                for (int ni = 0; ni < 6; ++ni)
                    acc[4 + mi][ni] = __builtin_amdgcn_mfma_f32_16x16x32_bf16(
                        af[mi], bfr[ni], acc[4 + mi][ni], 0, 0, 0);
            __builtin_amdgcn_s_setprio(0);
            BARRIER();
        }
        // ---- P2: (kh1, mh0) + bfr(kh1); stage B1(kt+1) ----
        if (pf) stageB(kt + 1, buf ^ 1, 1);
        {
            bf16x8 af[4];
#pragma unroll
            for (int ni = 0; ni < 6; ++ni)
                bfr[ni] = *(const bf16x8*)&Bb[(wno + ni * 16 + lrow) * 64 + rc1];
#pragma unroll
            for (int mi = 0; mi < 4; ++mi)
                af[mi] = *(const bf16x8*)&Ab[(wmo + mi * 16 + lrow) * 64 + rc1];
            BARRIER();
            __builtin_amdgcn_s_setprio(1);
#pragma unroll
            for (int mi = 0; mi < 4; ++mi)
#pragma unroll
                for (int ni = 0; ni < 6; ++ni)
                    acc[mi][ni] = __builtin_amdgcn_mfma_f32_16x16x32_bf16(
                        af[mi], bfr[ni], acc[mi][ni], 0, 0, 0);
            __builtin_amdgcn_s_setprio(0);
            BARRIER();
        }
        // ---- P3: (kh1, mh1); vmcnt(0) (youngest stage ~1 phase old) ----
        {
            bf16x8 af[4];
#pragma unroll
            for (int mi = 0; mi < 4; ++mi)
                af[mi] = *(const bf16x8*)&Ab[(wmo + 64 + mi * 16 + lrow) * 64 + rc1];
            BARRIER();
            __builtin_amdgcn_s_setprio(1);
#pragma unroll
            for (int mi = 0; mi < 4; ++mi)
#pragma unroll
                for (int ni = 0; ni < 6; ++ni)
                    acc[4 + mi][ni] = __builtin_amdgcn_mfma_f32_16x16x32_bf16(
                        af[mi], bfr[ni], acc[4 + mi][ni], 0, 0, 0);
            __builtin_amdgcn_s_setprio(0);
            if (pf) asm volatile("s_waitcnt vmcnt(0)" ::: "memory");
            BARRIER();   // trailing: stage(kt+1) landed + slot reads done
        }
        buf ^= 1;
    }

    // epilogue: q/k/v boundaries (2048, 4096) are 16-aligned
    const int rq = (lane >> 4) << 2, cn = lane & 15;
#pragma unroll
    for (int mi = 0; mi < 8; ++mi)
#pragma unroll
        for (int ni = 0; ni < 6; ++ni) {
            int col = n0 + wno + ni * 16 + cn;
            float bv = bias[col];
            if (col >= 2 * NF) {
                bf16x4 o;
#pragma unroll
                for (int r = 0; r < 4; ++r) o[r] = (__bf16)(acc[mi][ni][r] + bv);
                int row = m0 + wmo + mi * 16 + rq;
                *(bf16x4*)&vT[(size_t)(col - 2 * NF) * T_DIM + row] = o;
            } else {
#pragma unroll
                for (int r = 0; r < 4; ++r) {
                    int row = m0 + wmo + mi * 16 + rq + r;
                    float val = acc[mi][ni][r] + bv;
                    if (col < NF)
                        qb[(size_t)row * NF + col] = (__bf16)val;
                    else
                        kb[(size_t)row * NF + (col - NF)] = (__bf16)val;
                }
            }
        }
}

// ---------------- 4. S = scale * q @ k^T (bf16; mask applied in softmax) ---
__global__ void __launch_bounds__(256)
sc_gemm_kernel(const __bf16* __restrict__ qb, const __bf16* __restrict__ kb,
               __bf16* __restrict__ S, const int* __restrict__ npadd_p) {
    int i = blockIdx.x;
    int mt = (int)((sqrtf(8.0f * (float)i + 1.0f) - 1.0f) * 0.5f);
    while ((mt + 1) * (mt + 2) / 2 <= i) ++mt;
    while (mt * (mt + 1) / 2 > i) --mt;
    int nt = i - mt * (mt + 1) / 2;
    const int m0 = mt * 128, n0 = nt * 128;
    const int npadd = *npadd_p;
    if (m0 + 128 <= npadd || n0 + 128 <= npadd) return;  // fully masked

    __shared__ __bf16 As[2 * 128 * 64];
    __shared__ __bf16 Bs[2 * 128 * 64];
    f32x4 acc[4][4] = {};
    gemm_loop(qb, kb, NF, NF, m0, n0, NF / 64, As, Bs, acc);

    const float scale = 0.022097086912079608f;  // 1/sqrt(2048)
    EPILOG_SETUP();
#pragma unroll
    for (int mi = 0; mi < 4; ++mi)
#pragma unroll
        for (int ni = 0; ni < 4; ++ni) {
            int j = n0 + wn + ni * 16 + cn;
#pragma unroll
            for (int r = 0; r < 4; ++r) {
                int row = m0 + wm + mi * 16 + rq + r;
                S[(size_t)row * T_DIM + j] = (__bf16)(acc[mi][ni][r] * scale);
            }
        }
}

// ---------------- 5. row softmax: one WAVE per row, no barriers ------------
__global__ void __launch_bounds__(256)
softmax_kernel(const __bf16* __restrict__ S, __bf16* __restrict__ P,
               const int* __restrict__ npadd_p) {
    const int wv = threadIdx.x >> 6, lane = threadIdx.x & 63;
    const int row = blockIdx.x * 4 + wv;
    const int npadd = *npadd_p;
    __bf16* prow = P + (size_t)row * T_DIM;

    if (row < npadd) {  // padding row: p == 0
        bf16x8 z = {};
#pragma unroll
        for (int c = 0; c < 8; ++c) ((bf16x8*)prow)[c * 64 + lane] = z;
        return;
    }

    const __bf16* srow = S + (size_t)row * T_DIM;
    float vals[64];
    float mx = NEGV;
#pragma unroll
    for (int c = 0; c < 8; ++c) {
        if (c * 512 > row) {  // wave-uniform skip
#pragma unroll
            for (int e = 0; e < 8; ++e) vals[c * 8 + e] = NEGV;
            continue;
        }
        int j0 = c * 512 + lane * 8;
        bf16x8 v = ((const bf16x8*)srow)[c * 64 + lane];
#pragma unroll
        for (int e = 0; e < 8; ++e) {
            float f = (j0 + e >= npadd && j0 + e <= row) ? (float)v[e] : NEGV;
            vals[c * 8 + e] = f;
            mx = fmaxf(mx, f);
        }
    }
#pragma unroll
    for (int o = 32; o > 0; o >>= 1) mx = fmaxf(mx, __shfl_xor(mx, o));

    float sm = 0.f;
#pragma unroll
    for (int k = 0; k < 64; ++k) {
        vals[k] = exp2f((vals[k] - mx) * 1.4426950408889634f);
        sm += vals[k];
    }
#pragma unroll
    for (int o = 32; o > 0; o >>= 1) sm += __shfl_xor(sm, o);
    float inv = 1.0f / sm;

#pragma unroll
    for (int c = 0; c < 8; ++c) {
        bf16x8 o;
#pragma unroll
        for (int e = 0; e < 8; ++e) o[e] = (__bf16)(vals[c * 8 + e] * inv);
        ((bf16x8*)prow)[c * 64 + lane] = o;
    }
}

// ---------------- 6. y = P @ V, split-K for the deep tiles -----------------
__global__ void __launch_bounds__(256)
pv_gemm_kernel(const __bf16* __restrict__ P, const __bf16* __restrict__ vT,
               float* __restrict__ out, const int* __restrict__ npadd_p) {
    const int idx = blockIdx.x;
    const int kskip = *npadd_p >> 6;  // BK=64 tiles fully inside padding
    int mt, nt, start, iters;
    bool atomic_out;
    if (idx < 256) {
        mt = idx & 15; nt = idx >> 4;
        int kt = (mt + 1) * 2 - kskip; if (kt < 0) kt = 0;
        start = kskip; iters = kt; atomic_out = false;
    } else {
        int j = idx - 256;
        mt = 16 + (j & 15); nt = (j >> 4) & 15;
        int half = j >> 8;
        int kt = (mt + 1) * 2 - kskip; if (kt < 0) kt = 0;
        int h0 = (kt + 1) >> 1;
        start = kskip + (half ? h0 : 0);
        iters = half ? kt - h0 : h0;
        atomic_out = true;
    }
    const int m0 = mt * 128, n0 = nt * 128;

    __shared__ __bf16 As[2 * 128 * 64];
    __shared__ __bf16 Bs[2 * 128 * 64];
    f32x4 acc[4][4] = {};
    gemm_loop(P + (size_t)start * 64, vT + (size_t)start * 64,
              T_DIM, T_DIM, m0, n0, iters, As, Bs, acc);

    EPILOG_SETUP();
#pragma unroll
    for (int mi = 0; mi < 4; ++mi)
#pragma unroll
        for (int ni = 0; ni < 4; ++ni) {
            int col = n0 + wn + ni * 16 + cn;
#pragma unroll
            for (int r = 0; r < 4; ++r) {
                int row = m0 + wm + mi * 16 + rq + r;
                float* p = &out[(size_t)row * NF + col];
                if (atomic_out) unsafeAtomicAdd(p, acc[mi][ni][r]);
                else            *p = acc[mi][ni][r];
            }
        }
}

extern "C" void kernel_launch(void* const* d_in, const int* in_sizes, int n_in,
                              void* d_out, int out_size, void* d_ws,
                              size_t ws_size, hipStream_t stream) {
    const float* x = (const float*)d_in[0];
    const float* W = (const float*)d_in[1];
    const float* b = (const float*)d_in[2];
    const int* npadd = (const int*)d_in[3];
    float* out = (float*)d_out;

    char* ws = (char*)d_ws;
    // layout (120 MB used):
    __bf16* xb = (__bf16*)(ws);                          // 16 MB [0,16)
    __bf16* Wt = (__bf16*)(ws + (16ull << 20));          // 24 MB [16,40)
    __bf16* qb = (__bf16*)(ws + (40ull << 20));          // 16 MB [40,56)
    __bf16* kb = (__bf16*)(ws + (56ull << 20));          // 16 MB [56,72)
    __bf16* vT = (__bf16*)(ws + (72ull << 20));          // 16 MB [72,88)
    __bf16* S  = (__bf16*)(ws + (88ull << 20));          // 32 MB [88,120)
    __bf16* P  = (__bf16*)(ws + (40ull << 20));          // 32 MB reuse qb+kb

    // zero the atomic-accumulated half of out (rows 2048..4095)
    hipMemsetAsync(out + (size_t)2048 * NF, 0, (size_t)2048 * NF * 4, stream);

    prep_kernel<<<2048 + (N3 / 32) * (C_DIM / 32), 256, 0, stream>>>(x, xb, W, Wt);
    qkv_gemm_kernel<<<dim3(T_DIM / 256, N3 / 384), 512, 0, stream>>>(xb, Wt, b,
                                                                     qb, kb, vT);
    sc_gemm_kernel<<<528, 256, 0, stream>>>(qb, kb, S, npadd);
    softmax_kernel<<<T_DIM / 4, 256, 0, stream>>>(S, P, npadd);
    pv_gemm_kernel<<<768, 256, 0, stream>>>(P, vT, out, npadd);
}